// Round 19
// baseline (65.409 us; speedup 1.0000x reference)
//
#include <hip/hip_runtime.h>
#include <math.h>

#define B_DIM 256
#define M_DIM 256
#define C_DIM 1024
#define C4    256            // C/4 float4 per row
#define UM_OFF (B_DIM * C_DIM)                       // 262144 floats
#define KL_OFF (UM_OFF + B_DIM * M_DIM * C_DIM)      // 67371008 floats
#define SCALE  0.03125f      // 1/sqrt(1024)

typedef float nfloat4 __attribute__((ext_vector_type(4)));

__device__ __forceinline__ void nt_store4(float4 v, float4* p) {
    nfloat4 n = {v.x, v.y, v.z, v.w};
    __builtin_nontemporal_store(n, (nfloat4*)p);
}
__device__ __forceinline__ float dot4(float4 a, float4 b) {
    return a.x*b.x + a.y*b.y + a.z*b.z + a.w*b.w;
}
__device__ __forceinline__ float wsum(float v) {
    #pragma unroll
    for (int off = 32; off; off >>= 1) v += __shfl_xor(v, off, 64);
    return v;
}
__device__ __forceinline__ float wmax(float v) {
    #pragma unroll
    for (int off = 32; off; off >>= 1) v = fmaxf(v, __shfl_xor(v, off, 64));
    return v;
}
__device__ __forceinline__ float4 blend9(float4 v, float4 xr) {
    return make_float4(0.9f*v.x + 0.1f*xr.x, 0.9f*v.y + 0.1f*xr.y,
                       0.9f*v.z + 0.1f*xr.z, 0.9f*v.w + 0.1f*xr.w);
}

// ---------------- K1: stream + free-rider sims. 8192 x 256.
// ONLY change vs R18: burst stores are NON-TEMPORAL (bypass L2 so the 268 MB
// write stream stops evicting the 1 MB mem working set).
__global__ __launch_bounds__(256) void tm_stream(const float* __restrict__ x,
                                                 const float* __restrict__ mem,
                                                 float* __restrict__ out) {
    const int j = blockIdx.x;       // 0..8191
    const int b  = j >> 5;
    const int m0 = (j & 31) << 3;   // 0,8,...,248
    const int t = threadIdx.x;      // column float4 id
    const int lane = t & 63;
    const int wv = t >> 6;          // 0..3

    __shared__ float s_p[8][4];     // [row][wave]

    const float4* src = (const float4*)mem + (m0 << 8) + t;
    float4 r0 = src[0 << 8];
    float4 r1 = src[1 << 8];
    float4 r2 = src[2 << 8];
    float4 r3 = src[3 << 8];
    float4 r4 = src[4 << 8];
    float4 r5 = src[5 << 8];
    float4 r6 = src[6 << 8];
    float4 r7 = src[7 << 8];
    const float4 xv = ((const float4*)(x + (size_t)b * C_DIM))[t];

    float p0 = dot4(r0, xv), p1 = dot4(r1, xv), p2 = dot4(r2, xv), p3 = dot4(r3, xv);
    float p4 = dot4(r4, xv), p5 = dot4(r5, xv), p6 = dot4(r6, xv), p7 = dot4(r7, xv);
    p0 = wsum(p0); p1 = wsum(p1); p2 = wsum(p2); p3 = wsum(p3);
    p4 = wsum(p4); p5 = wsum(p5); p6 = wsum(p6); p7 = wsum(p7);
    if (lane == 0) {
        s_p[0][wv] = p0; s_p[1][wv] = p1; s_p[2][wv] = p2; s_p[3][wv] = p3;
        s_p[4][wv] = p4; s_p[5][wv] = p5; s_p[6][wv] = p6; s_p[7][wv] = p7;
    }
    __syncthreads();
    if (t < 8)
        out[(size_t)b * C_DIM + m0 + t] = s_p[t][0] + s_p[t][1] + s_p[t][2] + s_p[t][3];

    float4* dst = (float4*)(out + UM_OFF) + ((size_t)b << 16) + (m0 << 8) + t;
    nt_store4(r0, dst + (0 << 8));
    nt_store4(r1, dst + (1 << 8));
    nt_store4(r2, dst + (2 << 8));
    nt_store4(r3, dst + (3 << 8));
    nt_store4(r4, dst + (4 << 8));
    nt_store4(r5, dst + (5 << 8));
    nt_store4(r6, dst + (6 << 8));
    nt_store4(r7, dst + (7 << 8));
}

// ---------------- K2: softmax + partial-z (R18 verbatim). 256 x 256.
__global__ __launch_bounds__(256) void tm_mid(const float* __restrict__ x,
                                              const float* __restrict__ mem,
                                              float* __restrict__ out,
                                              float* __restrict__ ws) {
    const int blk = blockIdx.x;     // 0..255
    const int gg = blk >> 2;
    const int qq = blk & 3;
    const int b0 = gg << 2;
    const int t = threadIdx.x;
    const int lane = t & 63;
    const int j = t >> 6;           // wave = batch offset
    const int b = b0 + j;

    __shared__ float s_attnT[64][4];   // [local m][batch j]

    const float4* mem4 = (const float4*)mem;

    const float* simsrow = out + (size_t)b * C_DIM;
    const float v0 = simsrow[lane];
    const float v1 = simsrow[lane + 64];
    const float v2 = simsrow[lane + 128];
    const float v3 = simsrow[lane + 192];
    const float4* x4 = (const float4*)(x + (size_t)b * C_DIM);
    const float4 xa = x4[lane], xb = x4[lane + 64];
    const float4 xc = x4[lane + 128], xd = x4[lane + 192];
    const float n2 = wsum(dot4(xa,xa) + dot4(xb,xb) + dot4(xc,xc) + dot4(xd,xd));

    float av = v0; int am = lane;
    if (v1 > av) { av = v1; am = lane + 64; }
    if (v2 > av) { av = v2; am = lane + 128; }
    if (v3 > av) { av = v3; am = lane + 192; }
    #pragma unroll
    for (int off = 32; off; off >>= 1) {
        float ov = __shfl_xor(av, off, 64);
        int   oi = __shfl_xor(am, off, 64);
        if (ov > av || (ov == av && oi < am)) { av = ov; am = oi; }
    }
    const int idx = am;
    const float fused = 0.9f * av + 0.1f * n2;

    float s0 = ((lane      ) == idx ? fused : v0) * SCALE;
    float s1 = ((lane +  64) == idx ? fused : v1) * SCALE;
    float s2 = ((lane + 128) == idx ? fused : v2) * SCALE;
    float s3 = ((lane + 192) == idx ? fused : v3) * SCALE;
    const float mx = wmax(fmaxf(fmaxf(s0, s1), fmaxf(s2, s3)));
    const float e0 = expf(s0 - mx), e1 = expf(s1 - mx);
    const float e2 = expf(s2 - mx), e3 = expf(s3 - mx);
    const float inv = 1.0f / wsum(e0 + e1 + e2 + e3);
    const float a0 = e0 * inv, a1 = e1 * inv, a2 = e2 * inv, a3 = e3 * inv;

    const float aq = (qq == 0) ? a0 : (qq == 1) ? a1 : (qq == 2) ? a2 : a3;
    s_attnT[lane][j] = aq;

    if (qq == 0) {
        float aidx;
        if      (idx <  64) aidx = __shfl(a0, idx,       64);
        else if (idx < 128) aidx = __shfl(a1, idx - 64,  64);
        else if (idx < 192) aidx = __shfl(a2, idx - 128, 64);
        else                aidx = __shfl(a3, idx - 192, 64);

        const float4* ir = mem4 + (idx << 8);
        float4 q0 = ir[lane], q1 = ir[lane+64], q2 = ir[lane+128], q3 = ir[lane+192];
        float p = 0.f; float4 dq;
        dq = make_float4(xa.x-q0.x, xa.y-q0.y, xa.z-q0.z, xa.w-q0.w); p += dot4(dq,dq);
        dq = make_float4(xb.x-q1.x, xb.y-q1.y, xb.z-q1.z, xb.w-q1.w); p += dot4(dq,dq);
        dq = make_float4(xc.x-q2.x, xc.y-q2.y, xc.z-q2.z, xc.w-q2.w); p += dot4(dq,dq);
        dq = make_float4(xd.x-q3.x, xd.y-q3.y, xd.z-q3.z, xd.w-q3.w); p += dot4(dq,dq);
        const float dwv = wsum(p);

        if (lane == 0) {
            ((int*)ws)[b]  = idx;
            ws[256 + b] = aidx * 0.1f;
            ws[512 + b] = dwv;
        }
    }
    __syncthreads();

    float4 z0 = make_float4(0,0,0,0), z1 = z0, z2 = z0, z3 = z0;
    const float4* src = mem4 + ((qq << 6) << 8) + t;
    const float4* attn4 = (const float4*)s_attnT;
    #pragma unroll 8
    for (int i = 0; i < 64; ++i) {
        float4 v = src[i << 8];
        float4 a = attn4[i];
        z0.x = fmaf(a.x, v.x, z0.x); z0.y = fmaf(a.x, v.y, z0.y);
        z0.z = fmaf(a.x, v.z, z0.z); z0.w = fmaf(a.x, v.w, z0.w);
        z1.x = fmaf(a.y, v.x, z1.x); z1.y = fmaf(a.y, v.y, z1.y);
        z1.z = fmaf(a.y, v.z, z1.z); z1.w = fmaf(a.y, v.w, z1.w);
        z2.x = fmaf(a.z, v.x, z2.x); z2.y = fmaf(a.z, v.y, z2.y);
        z2.z = fmaf(a.z, v.z, z2.z); z2.w = fmaf(a.z, v.w, z2.w);
        z3.x = fmaf(a.w, v.x, z3.x); z3.y = fmaf(a.w, v.y, z3.y);
        z3.z = fmaf(a.w, v.z, z3.z); z3.w = fmaf(a.w, v.w, z3.w);
    }
    float4* umb = (float4*)(out + UM_OFF);
    umb[((size_t)(b0 + 0) << 16) + (qq << 8) + t] = z0;
    umb[((size_t)(b0 + 1) << 16) + (qq << 8) + t] = z1;
    umb[((size_t)(b0 + 2) << 16) + (qq << 8) + t] = z2;
    umb[((size_t)(b0 + 3) << 16) + (qq << 8) + t] = z3;
}

// ---------------- K3: combine + kl + restore + blend (R18 verbatim). 256 x 256.
__global__ __launch_bounds__(256) void tm_fin(const float* __restrict__ x,
                                              const float* __restrict__ mem,
                                              float* __restrict__ out,
                                              const float* __restrict__ ws) {
    const int b = blockIdx.x;
    const int t = threadIdx.x;
    const int lane = t & 63;
    const int wv = t >> 6;
    __shared__ float s_w[4];

    const int   idx  = ((const int*)ws)[b];
    const float aidx = ws[256 + b];
    const float dw   = ws[512 + b];

    const float4* mem4 = (const float4*)mem;
    float4* um = (float4*)(out + UM_OFF) + ((size_t)b << 16);

    float4 p0 = um[(0 << 8) + t];
    float4 p1 = um[(1 << 8) + t];
    float4 p2 = um[(2 << 8) + t];
    float4 p3 = um[(3 << 8) + t];
    const float4 xv = ((const float4*)(x + (size_t)b * C_DIM))[t];
    float4 sl = mem4[(idx << 8) + t];

    float4 d = make_float4(xv.x - sl.x, xv.y - sl.y, xv.z - sl.z, xv.w - sl.w);
    float4 z;
    z.x = p0.x + p1.x + p2.x + p3.x + aidx * d.x;
    z.y = p0.y + p1.y + p2.y + p3.y + aidx * d.y;
    z.z = p0.z + p1.z + p2.z + p3.z + aidx * d.z;
    z.w = p0.w + p1.w + p2.w + p3.w + aidx * d.w;

    float ex = z.x - xv.x, ey = z.y - xv.y, ez = z.z - xv.z, ew = z.w - xv.w;
    float drp = ex*ex + ey*ey + ez*ez + ew*ew;

    ((float4*)out)[(size_t)b * C4 + t] = z;     // overwrites sims stash

    #pragma unroll
    for (int r = 0; r < 4; ++r) {
        float4 v = mem4[(r << 8) + t];
        if (idx == r) v = blend9(v, xv);
        um[(r << 8) + t] = v;
    }
    if (idx >= 4) um[(idx << 8) + t] = blend9(sl, xv);

    const float s = wsum(drp);
    if (lane == 0) s_w[wv] = s;
    __syncthreads();
    if (t == 0)
        out[KL_OFF + b] = 0.5f * (dw + s_w[0] + s_w[1] + s_w[2] + s_w[3]);
}

extern "C" void kernel_launch(void* const* d_in, const int* in_sizes, int n_in,
                              void* d_out, int out_size, void* d_ws, size_t ws_size,
                              hipStream_t stream) {
    const float* x   = (const float*)d_in[0];   // input_encoded [B, C]
    const float* mem = (const float*)d_in[1];   // memory_mean  [M, C]
    float* out = (float*)d_out;
    float* ws  = (float*)d_ws;

    tm_stream<<<dim3(8192), dim3(256), 0, stream>>>(x, mem, out);
    tm_mid<<<dim3(256), dim3(256), 0, stream>>>(x, mem, out, ws);
    tm_fin<<<dim3(256), dim3(256), 0, stream>>>(x, mem, out, ws);
}

// Round 20
// 58.226 us; speedup vs baseline: 1.1234x; 1.1234x over previous
//
#include <hip/hip_runtime.h>
#include <math.h>

#define B_DIM 256
#define M_DIM 256
#define C_DIM 1024
#define C4    256            // C/4 float4 per row
#define UM_OFF (B_DIM * C_DIM)                       // 262144 floats
#define KL_OFF (UM_OFF + B_DIM * M_DIM * C_DIM)      // 67371008 floats
#define SCALE  0.03125f      // 1/sqrt(1024)

__device__ __forceinline__ float dot4(float4 a, float4 b) {
    return a.x*b.x + a.y*b.y + a.z*b.z + a.w*b.w;
}
__device__ __forceinline__ float wsum(float v) {
    #pragma unroll
    for (int off = 32; off; off >>= 1) v += __shfl_xor(v, off, 64);
    return v;
}
__device__ __forceinline__ float wmax(float v) {
    #pragma unroll
    for (int off = 32; off; off >>= 1) v = fmaxf(v, __shfl_xor(v, off, 64));
    return v;
}
__device__ __forceinline__ float4 blend9(float4 v, float4 xr) {
    return make_float4(0.9f*v.x + 0.1f*xr.x, 0.9f*v.y + 0.1f*xr.y,
                       0.9f*v.z + 0.1f*xr.z, 0.9f*v.w + 0.1f*xr.w);
}

// ---------------- K1: stream + free-rider sims. 8192 x 256.
// vs R18: store burst issued IMMEDIATELY after loads (before the shfl-reduce
// phase) so the write drain overlaps each block's VALU reduction. Regular
// stores (R19 proved nt stores are 13% slower here).
__global__ __launch_bounds__(256) void tm_stream(const float* __restrict__ x,
                                                 const float* __restrict__ mem,
                                                 float* __restrict__ out) {
    const int j = blockIdx.x;       // 0..8191
    const int b  = j >> 5;
    const int m0 = (j & 31) << 3;   // 0,8,...,248
    const int t = threadIdx.x;      // column float4 id
    const int lane = t & 63;
    const int wv = t >> 6;          // 0..3

    __shared__ float s_p[8][4];     // [row][wave]

    const float4* src = (const float4*)mem + (m0 << 8) + t;
    float4 r0 = src[0 << 8];
    float4 r1 = src[1 << 8];
    float4 r2 = src[2 << 8];
    float4 r3 = src[3 << 8];
    float4 r4 = src[4 << 8];
    float4 r5 = src[5 << 8];
    float4 r6 = src[6 << 8];
    float4 r7 = src[7 << 8];
    const float4 xv = ((const float4*)(x + (size_t)b * C_DIM))[t];

    // store burst FIRST (no dependence on the reduction below)
    float4* dst = (float4*)(out + UM_OFF) + ((size_t)b << 16) + (m0 << 8) + t;
    dst[0 << 8] = r0;
    dst[1 << 8] = r1;
    dst[2 << 8] = r2;
    dst[3 << 8] = r3;
    dst[4 << 8] = r4;
    dst[5 << 8] = r5;
    dst[6 << 8] = r6;
    dst[7 << 8] = r7;

    // sims from the same registers, draining under the stores
    float p0 = dot4(r0, xv), p1 = dot4(r1, xv), p2 = dot4(r2, xv), p3 = dot4(r3, xv);
    float p4 = dot4(r4, xv), p5 = dot4(r5, xv), p6 = dot4(r6, xv), p7 = dot4(r7, xv);
    p0 = wsum(p0); p1 = wsum(p1); p2 = wsum(p2); p3 = wsum(p3);
    p4 = wsum(p4); p5 = wsum(p5); p6 = wsum(p6); p7 = wsum(p7);
    if (lane == 0) {
        s_p[0][wv] = p0; s_p[1][wv] = p1; s_p[2][wv] = p2; s_p[3][wv] = p3;
        s_p[4][wv] = p4; s_p[5][wv] = p5; s_p[6][wv] = p6; s_p[7][wv] = p7;
    }
    __syncthreads();
    if (t < 8)
        out[(size_t)b * C_DIM + m0 + t] = s_p[t][0] + s_p[t][1] + s_p[t][2] + s_p[t][3];
}

// ---------------- K2: softmax + partial-z (R18 verbatim). 256 x 256.
__global__ __launch_bounds__(256) void tm_mid(const float* __restrict__ x,
                                              const float* __restrict__ mem,
                                              float* __restrict__ out,
                                              float* __restrict__ ws) {
    const int blk = blockIdx.x;     // 0..255
    const int gg = blk >> 2;
    const int qq = blk & 3;
    const int b0 = gg << 2;
    const int t = threadIdx.x;
    const int lane = t & 63;
    const int j = t >> 6;           // wave = batch offset
    const int b = b0 + j;

    __shared__ float s_attnT[64][4];   // [local m][batch j]

    const float4* mem4 = (const float4*)mem;

    const float* simsrow = out + (size_t)b * C_DIM;
    const float v0 = simsrow[lane];
    const float v1 = simsrow[lane + 64];
    const float v2 = simsrow[lane + 128];
    const float v3 = simsrow[lane + 192];
    const float4* x4 = (const float4*)(x + (size_t)b * C_DIM);
    const float4 xa = x4[lane], xb = x4[lane + 64];
    const float4 xc = x4[lane + 128], xd = x4[lane + 192];
    const float n2 = wsum(dot4(xa,xa) + dot4(xb,xb) + dot4(xc,xc) + dot4(xd,xd));

    float av = v0; int am = lane;
    if (v1 > av) { av = v1; am = lane + 64; }
    if (v2 > av) { av = v2; am = lane + 128; }
    if (v3 > av) { av = v3; am = lane + 192; }
    #pragma unroll
    for (int off = 32; off; off >>= 1) {
        float ov = __shfl_xor(av, off, 64);
        int   oi = __shfl_xor(am, off, 64);
        if (ov > av || (ov == av && oi < am)) { av = ov; am = oi; }
    }
    const int idx = am;
    const float fused = 0.9f * av + 0.1f * n2;

    float s0 = ((lane      ) == idx ? fused : v0) * SCALE;
    float s1 = ((lane +  64) == idx ? fused : v1) * SCALE;
    float s2 = ((lane + 128) == idx ? fused : v2) * SCALE;
    float s3 = ((lane + 192) == idx ? fused : v3) * SCALE;
    const float mx = wmax(fmaxf(fmaxf(s0, s1), fmaxf(s2, s3)));
    const float e0 = expf(s0 - mx), e1 = expf(s1 - mx);
    const float e2 = expf(s2 - mx), e3 = expf(s3 - mx);
    const float inv = 1.0f / wsum(e0 + e1 + e2 + e3);
    const float a0 = e0 * inv, a1 = e1 * inv, a2 = e2 * inv, a3 = e3 * inv;

    const float aq = (qq == 0) ? a0 : (qq == 1) ? a1 : (qq == 2) ? a2 : a3;
    s_attnT[lane][j] = aq;

    if (qq == 0) {
        float aidx;
        if      (idx <  64) aidx = __shfl(a0, idx,       64);
        else if (idx < 128) aidx = __shfl(a1, idx - 64,  64);
        else if (idx < 192) aidx = __shfl(a2, idx - 128, 64);
        else                aidx = __shfl(a3, idx - 192, 64);

        const float4* ir = mem4 + (idx << 8);
        float4 q0 = ir[lane], q1 = ir[lane+64], q2 = ir[lane+128], q3 = ir[lane+192];
        float p = 0.f; float4 dq;
        dq = make_float4(xa.x-q0.x, xa.y-q0.y, xa.z-q0.z, xa.w-q0.w); p += dot4(dq,dq);
        dq = make_float4(xb.x-q1.x, xb.y-q1.y, xb.z-q1.z, xb.w-q1.w); p += dot4(dq,dq);
        dq = make_float4(xc.x-q2.x, xc.y-q2.y, xc.z-q2.z, xc.w-q2.w); p += dot4(dq,dq);
        dq = make_float4(xd.x-q3.x, xd.y-q3.y, xd.z-q3.z, xd.w-q3.w); p += dot4(dq,dq);
        const float dwv = wsum(p);

        if (lane == 0) {
            ((int*)ws)[b]  = idx;
            ws[256 + b] = aidx * 0.1f;
            ws[512 + b] = dwv;
        }
    }
    __syncthreads();

    float4 z0 = make_float4(0,0,0,0), z1 = z0, z2 = z0, z3 = z0;
    const float4* src = mem4 + ((qq << 6) << 8) + t;
    const float4* attn4 = (const float4*)s_attnT;
    #pragma unroll 8
    for (int i = 0; i < 64; ++i) {
        float4 v = src[i << 8];
        float4 a = attn4[i];
        z0.x = fmaf(a.x, v.x, z0.x); z0.y = fmaf(a.x, v.y, z0.y);
        z0.z = fmaf(a.x, v.z, z0.z); z0.w = fmaf(a.x, v.w, z0.w);
        z1.x = fmaf(a.y, v.x, z1.x); z1.y = fmaf(a.y, v.y, z1.y);
        z1.z = fmaf(a.y, v.z, z1.z); z1.w = fmaf(a.y, v.w, z1.w);
        z2.x = fmaf(a.z, v.x, z2.x); z2.y = fmaf(a.z, v.y, z2.y);
        z2.z = fmaf(a.z, v.z, z2.z); z2.w = fmaf(a.z, v.w, z2.w);
        z3.x = fmaf(a.w, v.x, z3.x); z3.y = fmaf(a.w, v.y, z3.y);
        z3.z = fmaf(a.w, v.z, z3.z); z3.w = fmaf(a.w, v.w, z3.w);
    }
    float4* umb = (float4*)(out + UM_OFF);
    umb[((size_t)(b0 + 0) << 16) + (qq << 8) + t] = z0;
    umb[((size_t)(b0 + 1) << 16) + (qq << 8) + t] = z1;
    umb[((size_t)(b0 + 2) << 16) + (qq << 8) + t] = z2;
    umb[((size_t)(b0 + 3) << 16) + (qq << 8) + t] = z3;
}

// ---------------- K3: combine + kl + restore + blend (R18 verbatim). 256 x 256.
__global__ __launch_bounds__(256) void tm_fin(const float* __restrict__ x,
                                              const float* __restrict__ mem,
                                              float* __restrict__ out,
                                              const float* __restrict__ ws) {
    const int b = blockIdx.x;
    const int t = threadIdx.x;
    const int lane = t & 63;
    const int wv = t >> 6;
    __shared__ float s_w[4];

    const int   idx  = ((const int*)ws)[b];
    const float aidx = ws[256 + b];
    const float dw   = ws[512 + b];

    const float4* mem4 = (const float4*)mem;
    float4* um = (float4*)(out + UM_OFF) + ((size_t)b << 16);

    float4 p0 = um[(0 << 8) + t];
    float4 p1 = um[(1 << 8) + t];
    float4 p2 = um[(2 << 8) + t];
    float4 p3 = um[(3 << 8) + t];
    const float4 xv = ((const float4*)(x + (size_t)b * C_DIM))[t];
    float4 sl = mem4[(idx << 8) + t];

    float4 d = make_float4(xv.x - sl.x, xv.y - sl.y, xv.z - sl.z, xv.w - sl.w);
    float4 z;
    z.x = p0.x + p1.x + p2.x + p3.x + aidx * d.x;
    z.y = p0.y + p1.y + p2.y + p3.y + aidx * d.y;
    z.z = p0.z + p1.z + p2.z + p3.z + aidx * d.z;
    z.w = p0.w + p1.w + p2.w + p3.w + aidx * d.w;

    float ex = z.x - xv.x, ey = z.y - xv.y, ez = z.z - xv.z, ew = z.w - xv.w;
    float drp = ex*ex + ey*ey + ez*ez + ew*ew;

    ((float4*)out)[(size_t)b * C4 + t] = z;     // overwrites sims stash

    #pragma unroll
    for (int r = 0; r < 4; ++r) {
        float4 v = mem4[(r << 8) + t];
        if (idx == r) v = blend9(v, xv);
        um[(r << 8) + t] = v;
    }
    if (idx >= 4) um[(idx << 8) + t] = blend9(sl, xv);

    const float s = wsum(drp);
    if (lane == 0) s_w[wv] = s;
    __syncthreads();
    if (t == 0)
        out[KL_OFF + b] = 0.5f * (dw + s_w[0] + s_w[1] + s_w[2] + s_w[3]);
}

extern "C" void kernel_launch(void* const* d_in, const int* in_sizes, int n_in,
                              void* d_out, int out_size, void* d_ws, size_t ws_size,
                              hipStream_t stream) {
    const float* x   = (const float*)d_in[0];   // input_encoded [B, C]
    const float* mem = (const float*)d_in[1];   // memory_mean  [M, C]
    float* out = (float*)d_out;
    float* ws  = (float*)d_ws;

    tm_stream<<<dim3(8192), dim3(256), 0, stream>>>(x, mem, out);
    tm_mid<<<dim3(256), dim3(256), 0, stream>>>(x, mem, out, ws);
    tm_fin<<<dim3(256), dim3(256), 0, stream>>>(x, mem, out, ws);
}

// Round 21
// 58.145 us; speedup vs baseline: 1.1249x; 1.0014x over previous
//
#include <hip/hip_runtime.h>
#include <math.h>

#define B_DIM 256
#define M_DIM 256
#define C_DIM 1024
#define C4    256            // C/4 float4 per row
#define UM_OFF (B_DIM * C_DIM)                       // 262144 floats
#define KL_OFF (UM_OFF + B_DIM * M_DIM * C_DIM)      // 67371008 floats
#define SCALE  0.03125f      // 1/sqrt(1024)

__device__ __forceinline__ float dot4(float4 a, float4 b) {
    return a.x*b.x + a.y*b.y + a.z*b.z + a.w*b.w;
}
__device__ __forceinline__ float wsum(float v) {
    #pragma unroll
    for (int off = 32; off; off >>= 1) v += __shfl_xor(v, off, 64);
    return v;
}
__device__ __forceinline__ float wmax(float v) {
    #pragma unroll
    for (int off = 32; off; off >>= 1) v = fmaxf(v, __shfl_xor(v, off, 64));
    return v;
}
__device__ __forceinline__ float4 blend9(float4 v, float4 xr) {
    return make_float4(0.9f*v.x + 0.1f*xr.x, 0.9f*v.y + 0.1f*xr.y,
                       0.9f*v.z + 0.1f*xr.z, 0.9f*v.w + 0.1f*xr.w);
}

// ---------------- K1: stream + free-rider sims, wave-owned rows. 8192 x 256.
// Wave wv owns rows m0+2wv, m0+2wv+1 COMPLETELY: loads 4 float4/row, stores
// them (same coalescing/bytes as R20), reduces each row's dot wave-internally
// (12 shfl/thread vs 48; NO LDS partials, NO barrier).
__global__ __launch_bounds__(256) void tm_stream(const float* __restrict__ x,
                                                 const float* __restrict__ mem,
                                                 float* __restrict__ out) {
    const int j = blockIdx.x;       // 0..8191
    const int b  = j >> 5;
    const int m0 = (j & 31) << 3;   // 0,8,...,248
    const int t = threadIdx.x;
    const int lane = t & 63;
    const int wv = t >> 6;          // 0..3

    const int rA = m0 + (wv << 1);      // even row of this wave
    const int rB = rA + 1;

    const float4* xr = (const float4*)(x + (size_t)b * C_DIM);
    const float4 x0 = xr[lane];
    const float4 x1 = xr[lane + 64];
    const float4 x2 = xr[lane + 128];
    const float4 x3 = xr[lane + 192];

    const float4* srcA = (const float4*)mem + (rA << 8);
    const float4* srcB = (const float4*)mem + (rB << 8);
    float4 a0 = srcA[lane];
    float4 a1 = srcA[lane + 64];
    float4 a2 = srcA[lane + 128];
    float4 a3 = srcA[lane + 192];
    float4 b0 = srcB[lane];
    float4 b1 = srcB[lane + 64];
    float4 b2 = srcB[lane + 128];
    float4 b3 = srcB[lane + 192];

    // store burst first (no dependence on the reductions)
    float4* base = (float4*)(out + UM_OFF) + ((size_t)b << 16);
    float4* dstA = base + (rA << 8);
    float4* dstB = base + (rB << 8);
    dstA[lane]       = a0;
    dstA[lane + 64]  = a1;
    dstA[lane + 128] = a2;
    dstA[lane + 192] = a3;
    dstB[lane]       = b0;
    dstB[lane + 64]  = b1;
    dstB[lane + 128] = b2;
    dstB[lane + 192] = b3;

    // wave-internal sims for the two owned rows
    float accA = dot4(a0, x0) + dot4(a1, x1) + dot4(a2, x2) + dot4(a3, x3);
    float accB = dot4(b0, x0) + dot4(b1, x1) + dot4(b2, x2) + dot4(b3, x3);
    accA = wsum(accA);
    accB = wsum(accB);
    if (lane == 0) {
        out[(size_t)b * C_DIM + rA] = accA;
        out[(size_t)b * C_DIM + rB] = accB;
    }
}

// ---------------- K2: softmax + partial-z (R18 verbatim). 256 x 256.
__global__ __launch_bounds__(256) void tm_mid(const float* __restrict__ x,
                                              const float* __restrict__ mem,
                                              float* __restrict__ out,
                                              float* __restrict__ ws) {
    const int blk = blockIdx.x;     // 0..255
    const int gg = blk >> 2;
    const int qq = blk & 3;
    const int b0 = gg << 2;
    const int t = threadIdx.x;
    const int lane = t & 63;
    const int j = t >> 6;           // wave = batch offset
    const int b = b0 + j;

    __shared__ float s_attnT[64][4];   // [local m][batch j]

    const float4* mem4 = (const float4*)mem;

    const float* simsrow = out + (size_t)b * C_DIM;
    const float v0 = simsrow[lane];
    const float v1 = simsrow[lane + 64];
    const float v2 = simsrow[lane + 128];
    const float v3 = simsrow[lane + 192];
    const float4* x4 = (const float4*)(x + (size_t)b * C_DIM);
    const float4 xa = x4[lane], xb = x4[lane + 64];
    const float4 xc = x4[lane + 128], xd = x4[lane + 192];
    const float n2 = wsum(dot4(xa,xa) + dot4(xb,xb) + dot4(xc,xc) + dot4(xd,xd));

    float av = v0; int am = lane;
    if (v1 > av) { av = v1; am = lane + 64; }
    if (v2 > av) { av = v2; am = lane + 128; }
    if (v3 > av) { av = v3; am = lane + 192; }
    #pragma unroll
    for (int off = 32; off; off >>= 1) {
        float ov = __shfl_xor(av, off, 64);
        int   oi = __shfl_xor(am, off, 64);
        if (ov > av || (ov == av && oi < am)) { av = ov; am = oi; }
    }
    const int idx = am;
    const float fused = 0.9f * av + 0.1f * n2;

    float s0 = ((lane      ) == idx ? fused : v0) * SCALE;
    float s1 = ((lane +  64) == idx ? fused : v1) * SCALE;
    float s2 = ((lane + 128) == idx ? fused : v2) * SCALE;
    float s3 = ((lane + 192) == idx ? fused : v3) * SCALE;
    const float mx = wmax(fmaxf(fmaxf(s0, s1), fmaxf(s2, s3)));
    const float e0 = expf(s0 - mx), e1 = expf(s1 - mx);
    const float e2 = expf(s2 - mx), e3 = expf(s3 - mx);
    const float inv = 1.0f / wsum(e0 + e1 + e2 + e3);
    const float a0 = e0 * inv, a1 = e1 * inv, a2 = e2 * inv, a3 = e3 * inv;

    const float aq = (qq == 0) ? a0 : (qq == 1) ? a1 : (qq == 2) ? a2 : a3;
    s_attnT[lane][j] = aq;

    if (qq == 0) {
        float aidx;
        if      (idx <  64) aidx = __shfl(a0, idx,       64);
        else if (idx < 128) aidx = __shfl(a1, idx - 64,  64);
        else if (idx < 192) aidx = __shfl(a2, idx - 128, 64);
        else                aidx = __shfl(a3, idx - 192, 64);

        const float4* ir = mem4 + (idx << 8);
        float4 q0 = ir[lane], q1 = ir[lane+64], q2 = ir[lane+128], q3 = ir[lane+192];
        float p = 0.f; float4 dq;
        dq = make_float4(xa.x-q0.x, xa.y-q0.y, xa.z-q0.z, xa.w-q0.w); p += dot4(dq,dq);
        dq = make_float4(xb.x-q1.x, xb.y-q1.y, xb.z-q1.z, xb.w-q1.w); p += dot4(dq,dq);
        dq = make_float4(xc.x-q2.x, xc.y-q2.y, xc.z-q2.z, xc.w-q2.w); p += dot4(dq,dq);
        dq = make_float4(xd.x-q3.x, xd.y-q3.y, xd.z-q3.z, xd.w-q3.w); p += dot4(dq,dq);
        const float dwv = wsum(p);

        if (lane == 0) {
            ((int*)ws)[b]  = idx;
            ws[256 + b] = aidx * 0.1f;
            ws[512 + b] = dwv;
        }
    }
    __syncthreads();

    float4 z0 = make_float4(0,0,0,0), z1 = z0, z2 = z0, z3 = z0;
    const float4* src = mem4 + ((qq << 6) << 8) + t;
    const float4* attn4 = (const float4*)s_attnT;
    #pragma unroll 8
    for (int i = 0; i < 64; ++i) {
        float4 v = src[i << 8];
        float4 a = attn4[i];
        z0.x = fmaf(a.x, v.x, z0.x); z0.y = fmaf(a.x, v.y, z0.y);
        z0.z = fmaf(a.x, v.z, z0.z); z0.w = fmaf(a.x, v.w, z0.w);
        z1.x = fmaf(a.y, v.x, z1.x); z1.y = fmaf(a.y, v.y, z1.y);
        z1.z = fmaf(a.y, v.z, z1.z); z1.w = fmaf(a.y, v.w, z1.w);
        z2.x = fmaf(a.z, v.x, z2.x); z2.y = fmaf(a.z, v.y, z2.y);
        z2.z = fmaf(a.z, v.z, z2.z); z2.w = fmaf(a.z, v.w, z2.w);
        z3.x = fmaf(a.w, v.x, z3.x); z3.y = fmaf(a.w, v.y, z3.y);
        z3.z = fmaf(a.w, v.z, z3.z); z3.w = fmaf(a.w, v.w, z3.w);
    }
    float4* umb = (float4*)(out + UM_OFF);
    umb[((size_t)(b0 + 0) << 16) + (qq << 8) + t] = z0;
    umb[((size_t)(b0 + 1) << 16) + (qq << 8) + t] = z1;
    umb[((size_t)(b0 + 2) << 16) + (qq << 8) + t] = z2;
    umb[((size_t)(b0 + 3) << 16) + (qq << 8) + t] = z3;
}

// ---------------- K3: combine + kl + restore + blend (R18 verbatim). 256 x 256.
__global__ __launch_bounds__(256) void tm_fin(const float* __restrict__ x,
                                              const float* __restrict__ mem,
                                              float* __restrict__ out,
                                              const float* __restrict__ ws) {
    const int b = blockIdx.x;
    const int t = threadIdx.x;
    const int lane = t & 63;
    const int wv = t >> 6;
    __shared__ float s_w[4];

    const int   idx  = ((const int*)ws)[b];
    const float aidx = ws[256 + b];
    const float dw   = ws[512 + b];

    const float4* mem4 = (const float4*)mem;
    float4* um = (float4*)(out + UM_OFF) + ((size_t)b << 16);

    float4 p0 = um[(0 << 8) + t];
    float4 p1 = um[(1 << 8) + t];
    float4 p2 = um[(2 << 8) + t];
    float4 p3 = um[(3 << 8) + t];
    const float4 xv = ((const float4*)(x + (size_t)b * C_DIM))[t];
    float4 sl = mem4[(idx << 8) + t];

    float4 d = make_float4(xv.x - sl.x, xv.y - sl.y, xv.z - sl.z, xv.w - sl.w);
    float4 z;
    z.x = p0.x + p1.x + p2.x + p3.x + aidx * d.x;
    z.y = p0.y + p1.y + p2.y + p3.y + aidx * d.y;
    z.z = p0.z + p1.z + p2.z + p3.z + aidx * d.z;
    z.w = p0.w + p1.w + p2.w + p3.w + aidx * d.w;

    float ex = z.x - xv.x, ey = z.y - xv.y, ez = z.z - xv.z, ew = z.w - xv.w;
    float drp = ex*ex + ey*ey + ez*ez + ew*ew;

    ((float4*)out)[(size_t)b * C4 + t] = z;     // overwrites sims stash

    #pragma unroll
    for (int r = 0; r < 4; ++r) {
        float4 v = mem4[(r << 8) + t];
        if (idx == r) v = blend9(v, xv);
        um[(r << 8) + t] = v;
    }
    if (idx >= 4) um[(idx << 8) + t] = blend9(sl, xv);

    const float s = wsum(drp);
    if (lane == 0) s_w[wv] = s;
    __syncthreads();
    if (t == 0)
        out[KL_OFF + b] = 0.5f * (dw + s_w[0] + s_w[1] + s_w[2] + s_w[3]);
}

extern "C" void kernel_launch(void* const* d_in, const int* in_sizes, int n_in,
                              void* d_out, int out_size, void* d_ws, size_t ws_size,
                              hipStream_t stream) {
    const float* x   = (const float*)d_in[0];   // input_encoded [B, C]
    const float* mem = (const float*)d_in[1];   // memory_mean  [M, C]
    float* out = (float*)d_out;
    float* ws  = (float*)d_ws;

    tm_stream<<<dim3(8192), dim3(256), 0, stream>>>(x, mem, out);
    tm_mid<<<dim3(256), dim3(256), 0, stream>>>(x, mem, out, ws);
    tm_fin<<<dim3(256), dim3(256), 0, stream>>>(x, mem, out, ws);
}